// Round 1
// baseline (300.417 us; speedup 1.0000x reference)
//
#include <hip/hip_runtime.h>
#include <cstdint>
#include <cstddef>

#define TOK   2048
#define DIMSZ 2048
#define D3    6144
#define NHEAD 32
#define HDIM  64

typedef __attribute__((ext_vector_type(8))) short bf16x8;
typedef __attribute__((ext_vector_type(8))) unsigned short u16x8;
typedef __attribute__((ext_vector_type(4))) float f32x4;

__device__ __forceinline__ float bf2f(unsigned short u){
  return __uint_as_float(((unsigned)u) << 16);
}
__device__ __forceinline__ unsigned short f2bf(float f){
  unsigned u = __float_as_uint(f);
  u += 0x7fffu + ((u >> 16) & 1u);   // RNE
  return (unsigned short)(u >> 16);
}
__device__ __forceinline__ void gload16(const void* g, void* l){
  __builtin_amdgcn_global_load_lds(
      (const __attribute__((address_space(1))) void*)g,
      (__attribute__((address_space(3))) void*)l, 16, 0, 0);
}
// in-place accumulate MFMA via inline asm: D==C tied, so no operand-overlap hazard
__device__ __forceinline__ void mfma16(bf16x8 a, bf16x8 b, f32x4& c){
  asm("v_mfma_f32_16x16x32_bf16 %0, %1, %2, %0" : "+v"(c) : "v"(a), "v"(b));
}

// ---------------- small prep kernels ----------------

__global__ __launch_bounds__(256) void cvt_bf16_kernel(
    const float* __restrict__ in, unsigned short* __restrict__ out, int n8){
  int i = blockIdx.x*256 + threadIdx.x;
  if (i >= n8) return;
  const float4* p = (const float4*)in + (size_t)i*2;
  float4 a = p[0], b = p[1];
  u16x8 o;
  o[0]=f2bf(a.x); o[1]=f2bf(a.y); o[2]=f2bf(a.z); o[3]=f2bf(a.w);
  o[4]=f2bf(b.x); o[5]=f2bf(b.y); o[6]=f2bf(b.z); o[7]=f2bf(b.w);
  *(u16x8*)(out + (size_t)i*8) = o;
}

// fp32 (R x C) -> bf16 (C x R)
__global__ __launch_bounds__(256) void transpose_cvt_kernel(
    const float* __restrict__ in, unsigned short* __restrict__ out, int R, int C){
  __shared__ float tile[32][33];
  int r0 = blockIdx.x*32, c0 = blockIdx.y*32;
  int tc = threadIdx.x & 31, tr = threadIdx.x >> 5;  // tr 0..7
  #pragma unroll
  for (int p=0;p<4;p++){ int r = tr + p*8; tile[r][tc] = in[(size_t)(r0+r)*C + (c0+tc)]; }
  __syncthreads();
  #pragma unroll
  for (int p=0;p<4;p++){ int r = tr + p*8; out[(size_t)(c0+r)*R + (r0+tc)] = f2bf(tile[tc][r]); }
}

__global__ __launch_bounds__(256) void gate_kernel(
    const float* __restrict__ x, const float* __restrict__ Wg,
    const float* __restrict__ bg, float* __restrict__ gate){
  int n = blockIdx.x;
  int h = threadIdx.x >> 3, j = threadIdx.x & 7;
  const float4* xr = (const float4*)(x + (size_t)n*DIMSZ);
  const float4* wr = (const float4*)(Wg + (size_t)h*DIMSZ);
  float s = 0.f;
  #pragma unroll 8
  for (int i=0;i<64;i++){
    float4 a = xr[j + i*8], b = wr[j + i*8];
    s += a.x*b.x + a.y*b.y + a.z*b.z + a.w*b.w;
  }
  s += __shfl_xor(s,1); s += __shfl_xor(s,2); s += __shfl_xor(s,4);
  if (j==0) gate[(size_t)h*TOK + n] = 2.f/(1.f + __expf(-(s + bg[h])));
}

// ---------------- GEMM (m97 structure): C[M,N] = A[M,K] @ Bt[N,K]^T ----------------
// MODE 0: Cbf = bf16(C + bias)     (QKV)
// MODE 1: Cf  = residual + (C + bias)*gate_mod   (out-proj, fp32)
template<int MODE>
__global__ __launch_bounds__(256) void gemm_bt(
    const unsigned short* __restrict__ A, const unsigned short* __restrict__ Bt,
    const float* __restrict__ bias,
    unsigned short* __restrict__ Cbf, float* __restrict__ Cf,
    const float* __restrict__ residual, const float* __restrict__ gate_mod,
    int M, int N, int K)
{
  __shared__ __align__(16) unsigned short ldsA[128*32];
  __shared__ __align__(16) unsigned short ldsB[128*32];
  const int tid  = threadIdx.x;
  const int w    = tid >> 6;
  const int lane = tid & 63;
  const int g    = lane >> 4;
  const int li   = lane & 15;
  const int bm   = blockIdx.x * 128;
  const int bn   = blockIdx.y * 128;
  const int wm   = (w >> 1) * 64;
  const int wn   = (w & 1) * 64;

  f32x4 acc[4][4];
  #pragma unroll
  for (int i=0;i<4;i++)
    #pragma unroll
    for (int j=0;j<4;j++)
      acc[i][j] = (f32x4){0.f,0.f,0.f,0.f};

  const int srow = lane >> 2;          // 0..15
  const int scb  = (lane & 3) * 16;    // byte col within 64B tile row

  for (int kt = 0; kt < K; kt += 32){
    #pragma unroll
    for (int i=0;i<2;i++){
      const int chunk = i*4 + w;
      const int row   = chunk*16 + srow;
      gload16((const char*)A  + ((size_t)(bm+row)*K + kt)*2 + scb, (char*)ldsA + chunk*1024);
      gload16((const char*)Bt + ((size_t)(bn+row)*K + kt)*2 + scb, (char*)ldsB + chunk*1024);
    }
    __syncthreads();
    bf16x8 af[4], bfr[4];
    #pragma unroll
    for (int mi=0;mi<4;mi++)
      af[mi] = *(const bf16x8*)((const char*)ldsA + (wm + mi*16 + li)*64 + g*16);
    #pragma unroll
    for (int ni=0;ni<4;ni++)
      bfr[ni] = *(const bf16x8*)((const char*)ldsB + (wn + ni*16 + li)*64 + g*16);
    #pragma unroll
    for (int mi=0;mi<4;mi++)
      #pragma unroll
      for (int ni=0;ni<4;ni++)
        mfma16(af[mi], bfr[ni], acc[mi][ni]);
    __syncthreads();
  }

  #pragma unroll
  for (int ni=0;ni<4;ni++){
    const int col = bn + wn + ni*16 + li;
    const float bv = bias[col];
    const float gm = (MODE==1) ? gate_mod[col] : 0.f;
    #pragma unroll
    for (int mi=0;mi<4;mi++){
      #pragma unroll
      for (int r=0;r<4;r++){
        const int row = bm + wm + mi*16 + g*4 + r;
        const float v = acc[mi][ni][r] + bv;
        if (MODE==0){
          Cbf[(size_t)row*N + col] = f2bf(v);
        } else {
          const size_t idx = (size_t)row*N + col;
          Cf[idx] = residual[idx] + v*gm;
        }
      }
    }
  }
}

// ---------------- RMSNorm + RoPE (Q scaled by 1/8), writes Q/K as (H,N,HD) bf16 ----------------
__global__ __launch_bounds__(256) void norm_rope_kernel(
    const unsigned short* __restrict__ qkv,
    const float* __restrict__ nqw, const float* __restrict__ nkw,
    const float* __restrict__ rc, const float* __restrict__ rsn,
    unsigned short* __restrict__ Q, unsigned short* __restrict__ Ko)
{
  const int n = blockIdx.x, t = threadIdx.x;
  __shared__ float red[4];
  #pragma unroll
  for (int qk=0; qk<2; qk++){
    const unsigned short* row = qkv + (size_t)n*D3 + qk*DIMSZ;
    u16x8 v = *(const u16x8*)(row + t*8);
    float f[8]; float ss = 0.f;
    #pragma unroll
    for (int j=0;j<8;j++){ f[j] = bf2f(v[j]); ss += f[j]*f[j]; }
    #pragma unroll
    for (int msk=1; msk<64; msk<<=1) ss += __shfl_xor(ss, msk);
    if ((t&63)==0) red[t>>6] = ss;
    __syncthreads();
    const float rs = rsqrtf((red[0]+red[1]+red[2]+red[3]) * (1.0f/2048.f) + 1e-6f);
    const int d = t*8, hd = d&63, h = d>>6;
    const int pd = (hd<32) ? d+32 : d-32;
    u16x8 pv = *(const u16x8*)(row + pd);
    const float* wv = qk ? nkw : nqw;
    const float* cs = rc  + n*64 + hd;
    const float* sn = rsn + n*64 + hd;
    const float scl = qk ? 1.f : 0.125f;
    const float sgn = (hd<32) ? -1.f : 1.f;
    u16x8 ov;
    #pragma unroll
    for (int j=0;j<8;j++){
      const float a = f[j]*rs*wv[d+j];
      const float b = bf2f(pv[j])*rs*wv[pd+j];
      ov[j] = f2bf((a*cs[j] + sgn*b*sn[j])*scl);
    }
    unsigned short* dst = (qk ? Ko : Q) + ((size_t)h*TOK + n)*HDIM + hd;
    *(u16x8*)dst = ov;
    __syncthreads();
  }
}

// ---------------- V transpose per head: qkv v-part (N,HD slice) -> Vt (H,HD,N) ----------------
__global__ __launch_bounds__(256) void v_transpose_kernel(
    const unsigned short* __restrict__ qkv, unsigned short* __restrict__ Vt){
  const int h = blockIdx.y, n0 = blockIdx.x*64;
  __shared__ unsigned short tile[64][65];
  const int t = threadIdx.x;
  const int i = t>>2, j0 = (t&3)*16;
  const unsigned short* src = qkv + (size_t)(n0+i)*D3 + 2*DIMSZ + h*HDIM + j0;
  #pragma unroll
  for (int q=0;q<16;q++) tile[i][j0+q] = src[q];
  __syncthreads();
  unsigned short* dst = Vt + ((size_t)h*HDIM + i)*TOK + n0 + j0;
  #pragma unroll
  for (int q=0;q<16;q++) dst[q] = tile[j0+q][i];
}

// ---------------- Flash attention: 64 q-rows/block, 4 waves x 16 rows, KVBLK=64 ----------------
__global__ __launch_bounds__(256) void flash_kernel(
    const unsigned short* __restrict__ Q, const unsigned short* __restrict__ K,
    const unsigned short* __restrict__ Vt, const float* __restrict__ gate,
    unsigned short* __restrict__ attn_out)
{
  __shared__ __align__(16) unsigned short ldsK[64*64];
  __shared__ __align__(16) unsigned short ldsV[64*64];
  __shared__ __align__(16) unsigned short ldsP[4*16*64];
  const int tid = threadIdx.x;
  const int w = tid >> 6, lane = tid & 63;
  const int g = lane >> 4, li = lane & 15;
  const int h = blockIdx.y, q0 = blockIdx.x * 64;

  const unsigned short* Qh = Q + (size_t)h*TOK*HDIM;
  bf16x8 qf0, qf1;
  {
    const int qrow = q0 + w*16 + li;
    qf0 = *(const bf16x8*)(Qh + (size_t)qrow*HDIM + g*8);
    qf1 = *(const bf16x8*)(Qh + (size_t)qrow*HDIM + 32 + g*8);
  }
  f32x4 O[4];
  float m_[4], l_[4];
  #pragma unroll
  for (int r=0;r<4;r++){ O[r]=(f32x4){0.f,0.f,0.f,0.f}; m_[r]=-1e30f; l_[r]=0.f; }

  const char* Kh = (const char*)(K  + (size_t)h*TOK*HDIM);   // 128B rows
  const char* Vh = (const char*)(Vt + (size_t)h*HDIM*TOK);   // 4096B rows
  const int srow = lane >> 3;                  // tile row mod 8 during staging
  const int scb  = ((lane & 7) ^ srow) * 16;   // pre-swizzled global source column
  char* pwb = (char*)ldsP + w*2048;
  const int xr = (li & 7) << 4;                // read-side xor for rows == li (mod 8)

  for (int kt = 0; kt < TOK; kt += 64){
    #pragma unroll
    for (int i=0;i<2;i++){
      const int chunk = i*4 + w;
      const int row = chunk*8 + srow;
      gload16(Kh + (size_t)(kt+row)*128 + scb, (char*)ldsK + chunk*1024);
      gload16(Vh + (size_t)row*4096 + (size_t)kt*2 + scb, (char*)ldsV + chunk*1024);
    }
    __syncthreads();

    // S = Q(16x64) @ K^T(64x64), swizzled LDS reads
    f32x4 sf[4];
    #pragma unroll
    for (int nn=0;nn<4;nn++) sf[nn]=(f32x4){0.f,0.f,0.f,0.f};
    #pragma unroll
    for (int c=0;c<2;c++){
      const bf16x8 qf = c ? qf1 : qf0;
      #pragma unroll
      for (int nn=0;nn<4;nn++){
        const int row = nn*16 + li;
        const bf16x8 kb = *(const bf16x8*)((const char*)ldsK + row*128 + ((c*64 + g*16) ^ xr));
        mfma16(qf, kb, sf[nn]);
      }
    }

    // online softmax (rows live in 16-lane groups)
    float mx[4];
    #pragma unroll
    for (int r=0;r<4;r++)
      mx[r] = fmaxf(fmaxf(sf[0][r], sf[1][r]), fmaxf(sf[2][r], sf[3][r]));
    #pragma unroll
    for (int msk=1; msk<16; msk<<=1){
      #pragma unroll
      for (int r=0;r<4;r++) mx[r] = fmaxf(mx[r], __shfl_xor(mx[r], msk));
    }
    float al[4], rs_[4];
    #pragma unroll
    for (int r=0;r<4;r++){
      const float nm = fmaxf(m_[r], mx[r]);
      al[r] = __expf(m_[r] - nm);
      m_[r] = nm;
      rs_[r] = 0.f;
    }
    #pragma unroll
    for (int nn=0;nn<4;nn++){
      #pragma unroll
      for (int r=0;r<4;r++){
        const float pv = __expf(sf[nn][r] - m_[r]);
        rs_[r] += pv;
        const int prow = g*4 + r;
        const int pcb = (nn*16 + li)*2;
        *(unsigned short*)(pwb + prow*128 + (pcb ^ ((prow&7)<<4))) = f2bf(pv);
      }
    }
    #pragma unroll
    for (int msk=1; msk<16; msk<<=1){
      #pragma unroll
      for (int r=0;r<4;r++) rs_[r] += __shfl_xor(rs_[r], msk);
    }
    f32x4 alv;
    #pragma unroll
    for (int r=0;r<4;r++){ l_[r] = l_[r]*al[r] + rs_[r]; alv[r] = al[r]; }
    #pragma unroll
    for (int nn=0;nn<4;nn++) O[nn] *= alv;
    __syncthreads();   // make P visible (and order vs staging)

    // O += P(16x64) @ V(64x64)
    #pragma unroll
    for (int c=0;c<2;c++){
      const bf16x8 pa = *(const bf16x8*)(pwb + li*128 + ((c*64 + g*16) ^ xr));
      #pragma unroll
      for (int nn=0;nn<4;nn++){
        const int row = nn*16 + li;
        const bf16x8 vb = *(const bf16x8*)((const char*)ldsV + row*128 + ((c*64 + g*16) ^ xr));
        mfma16(pa, vb, O[nn]);
      }
    }
    __syncthreads();   // protect ldsK/ldsV before next staging
  }

  #pragma unroll
  for (int r=0;r<4;r++){
    const int row = q0 + w*16 + g*4 + r;
    const float gv = gate[(size_t)h*TOK + row];
    const float sc = gv / l_[r];
    #pragma unroll
    for (int nn=0;nn<4;nn++)
      attn_out[(size_t)row*DIMSZ + h*HDIM + nn*16 + li] = f2bf(O[nn][r]*sc);
  }
}

// ---------------- launch ----------------

extern "C" void kernel_launch(void* const* d_in, const int* in_sizes, int n_in,
                              void* d_out, int out_size, void* d_ws, size_t ws_size,
                              hipStream_t stream)
{
  const float* x        = (const float*)d_in[0];
  const float* W_qkv    = (const float*)d_in[1];
  const float* b_qkv    = (const float*)d_in[2];
  const float* nq_w     = (const float*)d_in[3];
  const float* nk_w     = (const float*)d_in[4];
  const float* W_gate   = (const float*)d_in[5];
  const float* b_gate   = (const float*)d_in[6];
  const float* W_out    = (const float*)d_in[7];
  const float* b_out    = (const float*)d_in[8];
  const float* rope_cos = (const float*)d_in[9];
  const float* rope_sin = (const float*)d_in[10];
  const float* residual = (const float*)d_in[11];
  const float* gate_mod = (const float*)d_in[12];
  float* out = (float*)d_out;

  char* p = (char*)d_ws;
  auto take = [&](size_t b)->char*{ char* q = p; p += (b + 255) & ~(size_t)255; return q; };
  unsigned short* x_bf   = (unsigned short*)take((size_t)TOK*DIMSZ*2);
  unsigned short* WqkvT  = (unsigned short*)take((size_t)D3*DIMSZ*2);
  unsigned short* WoutT  = (unsigned short*)take((size_t)DIMSZ*DIMSZ*2);
  unsigned short* qkv    = (unsigned short*)take((size_t)TOK*D3*2);
  unsigned short* Qb     = (unsigned short*)take((size_t)NHEAD*TOK*HDIM*2);
  unsigned short* Kb     = (unsigned short*)take((size_t)NHEAD*TOK*HDIM*2);
  unsigned short* Vtb    = (unsigned short*)take((size_t)NHEAD*HDIM*TOK*2);
  unsigned short* attn_g = (unsigned short*)take((size_t)TOK*DIMSZ*2);
  float*          gateb  = (float*)take((size_t)NHEAD*TOK*4);

  cvt_bf16_kernel<<<(TOK*DIMSZ/8 + 255)/256, 256, 0, stream>>>(x, x_bf, TOK*DIMSZ/8);
  transpose_cvt_kernel<<<dim3(DIMSZ/32, D3/32),   256, 0, stream>>>(W_qkv, WqkvT, DIMSZ, D3);
  transpose_cvt_kernel<<<dim3(DIMSZ/32, DIMSZ/32),256, 0, stream>>>(W_out, WoutT, DIMSZ, DIMSZ);
  gate_kernel<<<TOK, 256, 0, stream>>>(x, W_gate, b_gate, gateb);
  gemm_bt<0><<<dim3(TOK/128, D3/128), 256, 0, stream>>>(
      x_bf, WqkvT, b_qkv, qkv, nullptr, nullptr, nullptr, TOK, D3, DIMSZ);
  norm_rope_kernel<<<TOK, 256, 0, stream>>>(qkv, nq_w, nk_w, rope_cos, rope_sin, Qb, Kb);
  v_transpose_kernel<<<dim3(TOK/64, NHEAD), 256, 0, stream>>>(qkv, Vtb);
  flash_kernel<<<dim3(TOK/64, NHEAD), 256, 0, stream>>>(Qb, Kb, Vtb, gateb, attn_g);
  gemm_bt<1><<<dim3(TOK/128, DIMSZ/128), 256, 0, stream>>>(
      attn_g, WoutT, b_out, nullptr, out, residual, gate_mod, TOK, DIMSZ, DIMSZ);
}

// Round 5
// 297.605 us; speedup vs baseline: 1.0094x; 1.0094x over previous
//
#include <hip/hip_runtime.h>
#include <cstdint>
#include <cstddef>

#define TOK   2048
#define DIMSZ 2048
#define D3    6144
#define NHEAD 32
#define HDIM  64

typedef __attribute__((ext_vector_type(8))) short bf16x8;
typedef __attribute__((ext_vector_type(8))) unsigned short u16x8;
typedef __attribute__((ext_vector_type(4))) float f32x4;

__device__ __forceinline__ float bf2f(unsigned short u){
  return __uint_as_float(((unsigned)u) << 16);
}
__device__ __forceinline__ unsigned short f2bf(float f){
  unsigned u = __float_as_uint(f);
  u += 0x7fffu + ((u >> 16) & 1u);   // RNE
  return (unsigned short)(u >> 16);
}
__device__ __forceinline__ void gload16(const void* g, void* l){
  __builtin_amdgcn_global_load_lds(
      (const __attribute__((address_space(1))) void*)g,
      (__attribute__((address_space(3))) void*)l, 16, 0, 0);
}
// gemm path: inline-asm MFMA (unchanged, passing)
__device__ __forceinline__ void mfma16(bf16x8 a, bf16x8 b, f32x4& c){
  asm("v_mfma_f32_16x16x32_bf16 %0, %1, %2, %0" : "+v"(c) : "v"(a), "v"(b));
}
// flash path: BUILTIN MFMA so the backend's hazard recognizer sees the opcode class
// (inline-asm MFMA is opaque to GCNHazardRecognizer -> missing MFMA-write/VALU-read
//  wait states; suspected cause of rounds 2-4 codegen-dependent corruption)
__device__ __forceinline__ void mfma16b(bf16x8 a, bf16x8 b, f32x4& c){
  c = __builtin_amdgcn_mfma_f32_16x16x32_bf16(a, b, c, 0, 0, 0);
}

// ---------------- small prep kernels ----------------

__global__ __launch_bounds__(256) void cvt_bf16_kernel(
    const float* __restrict__ in, unsigned short* __restrict__ out, int n8){
  int i = blockIdx.x*256 + threadIdx.x;
  if (i >= n8) return;
  const float4* p = (const float4*)in + (size_t)i*2;
  float4 a = p[0], b = p[1];
  u16x8 o;
  o[0]=f2bf(a.x); o[1]=f2bf(a.y); o[2]=f2bf(a.z); o[3]=f2bf(a.w);
  o[4]=f2bf(b.x); o[5]=f2bf(b.y); o[6]=f2bf(b.z); o[7]=f2bf(b.w);
  *(u16x8*)(out + (size_t)i*8) = o;
}

// fp32 (R x C) -> bf16 (C x R)
__global__ __launch_bounds__(256) void transpose_cvt_kernel(
    const float* __restrict__ in, unsigned short* __restrict__ out, int R, int C){
  __shared__ float tile[32][33];
  int r0 = blockIdx.x*32, c0 = blockIdx.y*32;
  int tc = threadIdx.x & 31, tr = threadIdx.x >> 5;  // tr 0..7
  #pragma unroll
  for (int p=0;p<4;p++){ int r = tr + p*8; tile[r][tc] = in[(size_t)(r0+r)*C + (c0+tc)]; }
  __syncthreads();
  #pragma unroll
  for (int p=0;p<4;p++){ int r = tr + p*8; out[(size_t)(c0+r)*R + (r0+tc)] = f2bf(tile[tc][r]); }
}

__global__ __launch_bounds__(256) void gate_kernel(
    const float* __restrict__ x, const float* __restrict__ Wg,
    const float* __restrict__ bg, float* __restrict__ gate){
  int n = blockIdx.x;
  int h = threadIdx.x >> 3, j = threadIdx.x & 7;
  const float4* xr = (const float4*)(x + (size_t)n*DIMSZ);
  const float4* wr = (const float4*)(Wg + (size_t)h*DIMSZ);
  float s = 0.f;
  #pragma unroll 8
  for (int i=0;i<64;i++){
    float4 a = xr[j + i*8], b = wr[j + i*8];
    s += a.x*b.x + a.y*b.y + a.z*b.z + a.w*b.w;
  }
  s += __shfl_xor(s,1); s += __shfl_xor(s,2); s += __shfl_xor(s,4);
  if (j==0) gate[(size_t)h*TOK + n] = 2.f/(1.f + __expf(-(s + bg[h])));
}

// ---------------- GEMM (m97 structure): C[M,N] = A[M,K] @ Bt[N,K]^T ----------------
template<int MODE>
__global__ __launch_bounds__(256) void gemm_bt(
    const unsigned short* __restrict__ A, const unsigned short* __restrict__ Bt,
    const float* __restrict__ bias,
    unsigned short* __restrict__ Cbf, float* __restrict__ Cf,
    const float* __restrict__ residual, const float* __restrict__ gate_mod,
    int M, int N, int K)
{
  __shared__ __align__(16) unsigned short ldsA[128*32];
  __shared__ __align__(16) unsigned short ldsB[128*32];
  const int tid  = threadIdx.x;
  const int w    = tid >> 6;
  const int lane = tid & 63;
  const int g    = lane >> 4;
  const int li   = lane & 15;
  const int bm   = blockIdx.x * 128;
  const int bn   = blockIdx.y * 128;
  const int wm   = (w >> 1) * 64;
  const int wn   = (w & 1) * 64;

  f32x4 acc[4][4];
  #pragma unroll
  for (int i=0;i<4;i++)
    #pragma unroll
    for (int j=0;j<4;j++)
      acc[i][j] = (f32x4){0.f,0.f,0.f,0.f};

  const int srow = lane >> 2;          // 0..15
  const int scb  = (lane & 3) * 16;    // byte col within 64B tile row

  for (int kt = 0; kt < K; kt += 32){
    #pragma unroll
    for (int i=0;i<2;i++){
      const int chunk = i*4 + w;
      const int row   = chunk*16 + srow;
      gload16((const char*)A  + ((size_t)(bm+row)*K + kt)*2 + scb, (char*)ldsA + chunk*1024);
      gload16((const char*)Bt + ((size_t)(bn+row)*K + kt)*2 + scb, (char*)ldsB + chunk*1024);
    }
    __syncthreads();
    bf16x8 af[4], bfr[4];
    #pragma unroll
    for (int mi=0;mi<4;mi++)
      af[mi] = *(const bf16x8*)((const char*)ldsA + (wm + mi*16 + li)*64 + g*16);
    #pragma unroll
    for (int ni=0;ni<4;ni++)
      bfr[ni] = *(const bf16x8*)((const char*)ldsB + (wn + ni*16 + li)*64 + g*16);
    #pragma unroll
    for (int mi=0;mi<4;mi++)
      #pragma unroll
      for (int ni=0;ni<4;ni++)
        mfma16(af[mi], bfr[ni], acc[mi][ni]);
    __syncthreads();
  }

  #pragma unroll
  for (int ni=0;ni<4;ni++){
    const int col = bn + wn + ni*16 + li;
    const float bv = bias[col];
    const float gm = (MODE==1) ? gate_mod[col] : 0.f;
    #pragma unroll
    for (int mi=0;mi<4;mi++){
      #pragma unroll
      for (int r=0;r<4;r++){
        const int row = bm + wm + mi*16 + g*4 + r;
        const float v = acc[mi][ni][r] + bv;
        if (MODE==0){
          Cbf[(size_t)row*N + col] = f2bf(v);
        } else {
          const size_t idx = (size_t)row*N + col;
          Cf[idx] = residual[idx] + v*gm;
        }
      }
    }
  }
}

// ---------------- RMSNorm + RoPE; Q scaled by (1/8)*log2(e) so softmax runs in exp2 domain ----------------
__global__ __launch_bounds__(256) void norm_rope_kernel(
    const unsigned short* __restrict__ qkv,
    const float* __restrict__ nqw, const float* __restrict__ nkw,
    const float* __restrict__ rc, const float* __restrict__ rsn,
    unsigned short* __restrict__ Q, unsigned short* __restrict__ Ko)
{
  const int n = blockIdx.x, t = threadIdx.x;
  __shared__ float red[4];
  #pragma unroll
  for (int qk=0; qk<2; qk++){
    const unsigned short* row = qkv + (size_t)n*D3 + qk*DIMSZ;
    u16x8 v = *(const u16x8*)(row + t*8);
    float f[8]; float ss = 0.f;
    #pragma unroll
    for (int j=0;j<8;j++){ f[j] = bf2f(v[j]); ss += f[j]*f[j]; }
    #pragma unroll
    for (int msk=1; msk<64; msk<<=1) ss += __shfl_xor(ss, msk);
    if ((t&63)==0) red[t>>6] = ss;
    __syncthreads();
    const float rs = rsqrtf((red[0]+red[1]+red[2]+red[3]) * (1.0f/2048.f) + 1e-6f);
    const int d = t*8, hd = d&63, h = d>>6;
    const int pd = (hd<32) ? d+32 : d-32;
    u16x8 pv = *(const u16x8*)(row + pd);
    const float* wv = qk ? nkw : nqw;
    const float* cs = rc  + n*64 + hd;
    const float* sn = rsn + n*64 + hd;
    const float scl = qk ? 1.f : (0.125f * 1.44269504088896340736f);
    const float sgn = (hd<32) ? -1.f : 1.f;
    u16x8 ov;
    #pragma unroll
    for (int j=0;j<8;j++){
      const float a = f[j]*rs*wv[d+j];
      const float b = bf2f(pv[j])*rs*wv[pd+j];
      ov[j] = f2bf((a*cs[j] + sgn*b*sn[j])*scl);
    }
    unsigned short* dst = (qk ? Ko : Q) + ((size_t)h*TOK + n)*HDIM + hd;
    *(u16x8*)dst = ov;
    __syncthreads();
  }
}

// ---------------- V transpose per head: qkv v-part (N,HD slice) -> Vt (H,HD,N) ----------------
__global__ __launch_bounds__(256) void v_transpose_kernel(
    const unsigned short* __restrict__ qkv, unsigned short* __restrict__ Vt){
  const int h = blockIdx.y, n0 = blockIdx.x*64;
  __shared__ unsigned short tile[64][65];
  const int t = threadIdx.x;
  const int i = t>>2, j0 = (t&3)*16;
  const unsigned short* src = qkv + (size_t)(n0+i)*D3 + 2*DIMSZ + h*HDIM + j0;
  #pragma unroll
  for (int q=0;q<16;q++) tile[i][j0+q] = src[q];
  __syncthreads();
  unsigned short* dst = Vt + ((size_t)h*HDIM + i)*TOK + n0 + j0;
  #pragma unroll
  for (int q=0;q<16;q++) dst[q] = tile[j0+q][i];
}

// ---------------- Flash attention v5: ROUND-1 STRUCTURE (single buffer, 3 barriers/tile,
// ---------------- full rescale every tile) + builtin MFMA + exp2 domain + lane-local l ----------------
__global__ __launch_bounds__(256) void flash_kernel(
    const unsigned short* __restrict__ Q, const unsigned short* __restrict__ K,
    const unsigned short* __restrict__ Vt, const float* __restrict__ gate,
    unsigned short* __restrict__ attn_out)
{
  __shared__ __align__(16) unsigned short ldsK[64*64];
  __shared__ __align__(16) unsigned short ldsV[64*64];
  __shared__ __align__(16) unsigned short ldsP[4*16*64];
  const int tid = threadIdx.x;
  const int w = tid >> 6, lane = tid & 63;
  const int g = lane >> 4, li = lane & 15;
  const int h = blockIdx.y, q0 = blockIdx.x * 64;

  const unsigned short* Qh = Q + (size_t)h*TOK*HDIM;
  bf16x8 qf0, qf1;
  {
    const int qrow = q0 + w*16 + li;
    qf0 = *(const bf16x8*)(Qh + (size_t)qrow*HDIM + g*8);
    qf1 = *(const bf16x8*)(Qh + (size_t)qrow*HDIM + 32 + g*8);
  }
  f32x4 O[4];
  float m_[4], l_[4];
  #pragma unroll
  for (int r=0;r<4;r++){ O[r]=(f32x4){0.f,0.f,0.f,0.f}; m_[r]=-1e30f; l_[r]=0.f; }

  const char* Kh = (const char*)(K  + (size_t)h*TOK*HDIM);   // 128B rows
  const char* Vh = (const char*)(Vt + (size_t)h*HDIM*TOK);   // 4096B rows
  const int srow = lane >> 3;                  // tile row mod 8 during staging
  const int scb  = ((lane & 7) ^ srow) * 16;   // pre-swizzled global source column
  char* pwb = (char*)ldsP + w*2048;
  const int xr = (li & 7) << 4;                // read-side xor for rows == li (mod 8)

  for (int kt = 0; kt < TOK; kt += 64){
    // stage KV tile into the single buffer (round-1 schedule)
    #pragma unroll
    for (int i=0;i<2;i++){
      const int chunk = i*4 + w;
      const int row = chunk*8 + srow;
      gload16(Kh + (size_t)(kt+row)*128 + scb, (char*)ldsK + chunk*1024);
      gload16(Vh + (size_t)row*4096 + (size_t)kt*2 + scb, (char*)ldsV + chunk*1024);
    }
    __syncthreads();   // S1: staging drained (vmcnt0 at barrier), K/V visible

    // S = Q(16x64) @ K^T(64x64) in exp2 domain (Q pre-scaled by 0.125*log2e)
    f32x4 sf[4];
    #pragma unroll
    for (int nn=0;nn<4;nn++) sf[nn]=(f32x4){0.f,0.f,0.f,0.f};
    #pragma unroll
    for (int c=0;c<2;c++){
      const bf16x8 qf = c ? qf1 : qf0;
      #pragma unroll
      for (int nn=0;nn<4;nn++){
        const int row = nn*16 + li;
        const bf16x8 kb = *(const bf16x8*)((const char*)ldsK + row*128 + ((c*64 + g*16) ^ xr));
        mfma16b(qf, kb, sf[nn]);
      }
    }

    // full 16-lane max reduce + rescale every tile (round-1 semantics)
    float mx[4];
    #pragma unroll
    for (int r=0;r<4;r++)
      mx[r] = fmaxf(fmaxf(sf[0][r], sf[1][r]), fmaxf(sf[2][r], sf[3][r]));
    #pragma unroll
    for (int msk=1; msk<16; msk<<=1){
      #pragma unroll
      for (int r=0;r<4;r++) mx[r] = fmaxf(mx[r], __shfl_xor(mx[r], msk));
    }
    f32x4 alv;
    #pragma unroll
    for (int r=0;r<4;r++){
      const float nm = fmaxf(m_[r], mx[r]);
      const float al = exp2f(m_[r] - nm);   // exactly 1.0f when max unchanged
      m_[r] = nm;
      l_[r] *= al;
      alv[r] = al;
    }
    #pragma unroll
    for (int nn=0;nn<4;nn++) O[nn] *= alv;

    // P = exp2(S - m) <= 1, lane-local l accumulation (cross-lane reduce in epilogue)
    #pragma unroll
    for (int nn=0;nn<4;nn++){
      #pragma unroll
      for (int r=0;r<4;r++){
        const float pv = exp2f(sf[nn][r] - m_[r]);
        l_[r] += pv;
        const int prow = g*4 + r;
        const int pcb = (nn*16 + li)*2;
        *(unsigned short*)(pwb + prow*128 + (pcb ^ ((prow&7)<<4))) = f2bf(pv);
      }
    }
    __syncthreads();   // S2: P visible

    // O += P(16x64) @ V(64x64)
    #pragma unroll
    for (int c=0;c<2;c++){
      const bf16x8 pa = *(const bf16x8*)(pwb + li*128 + ((c*64 + g*16) ^ xr));
      #pragma unroll
      for (int nn=0;nn<4;nn++){
        const int row = nn*16 + li;
        const bf16x8 vb = *(const bf16x8*)((const char*)ldsV + row*128 + ((c*64 + g*16) ^ xr));
        mfma16b(pa, vb, O[nn]);
      }
    }
    __syncthreads();   // S3: all reads done before next stage overwrites
  }

  // epilogue: single cross-lane sum reduce of l partials
  #pragma unroll
  for (int msk=1; msk<16; msk<<=1){
    #pragma unroll
    for (int r=0;r<4;r++) l_[r] += __shfl_xor(l_[r], msk);
  }
  #pragma unroll
  for (int r=0;r<4;r++){
    const int row = q0 + w*16 + g*4 + r;
    const float gv = gate[(size_t)h*TOK + row];
    const float sc = gv / l_[r];
    #pragma unroll
    for (int nn=0;nn<4;nn++)
      attn_out[(size_t)row*DIMSZ + h*HDIM + nn*16 + li] = f2bf(O[nn][r]*sc);
  }
}

// ---------------- launch ----------------

extern "C" void kernel_launch(void* const* d_in, const int* in_sizes, int n_in,
                              void* d_out, int out_size, void* d_ws, size_t ws_size,
                              hipStream_t stream)
{
  const float* x        = (const float*)d_in[0];
  const float* W_qkv    = (const float*)d_in[1];
  const float* b_qkv    = (const float*)d_in[2];
  const float* nq_w     = (const float*)d_in[3];
  const float* nk_w     = (const float*)d_in[4];
  const float* W_gate   = (const float*)d_in[5];
  const float* b_gate   = (const float*)d_in[6];
  const float* W_out    = (const float*)d_in[7];
  const float* b_out    = (const float*)d_in[8];
  const float* rope_cos = (const float*)d_in[9];
  const float* rope_sin = (const float*)d_in[10];
  const float* residual = (const float*)d_in[11];
  const float* gate_mod = (const float*)d_in[12];
  float* out = (float*)d_out;

  char* p = (char*)d_ws;
  auto take = [&](size_t b)->char*{ char* q = p; p += (b + 255) & ~(size_t)255; return q; };
  unsigned short* x_bf   = (unsigned short*)take((size_t)TOK*DIMSZ*2);
  unsigned short* WqkvT  = (unsigned short*)take((size_t)D3*DIMSZ*2);
  unsigned short* WoutT  = (unsigned short*)take((size_t)DIMSZ*DIMSZ*2);
  unsigned short* qkv    = (unsigned short*)take((size_t)TOK*D3*2);
  unsigned short* Qb     = (unsigned short*)take((size_t)NHEAD*TOK*HDIM*2);
  unsigned short* Kb     = (unsigned short*)take((size_t)NHEAD*TOK*HDIM*2);
  unsigned short* Vtb    = (unsigned short*)take((size_t)NHEAD*HDIM*TOK*2);
  unsigned short* attn_g = (unsigned short*)take((size_t)TOK*DIMSZ*2);
  float*          gateb  = (float*)take((size_t)NHEAD*TOK*4);

  cvt_bf16_kernel<<<(TOK*DIMSZ/8 + 255)/256, 256, 0, stream>>>(x, x_bf, TOK*DIMSZ/8);
  transpose_cvt_kernel<<<dim3(DIMSZ/32, D3/32),   256, 0, stream>>>(W_qkv, WqkvT, DIMSZ, D3);
  transpose_cvt_kernel<<<dim3(DIMSZ/32, DIMSZ/32),256, 0, stream>>>(W_out, WoutT, DIMSZ, DIMSZ);
  gate_kernel<<<TOK, 256, 0, stream>>>(x, W_gate, b_gate, gateb);
  gemm_bt<0><<<dim3(TOK/128, D3/128), 256, 0, stream>>>(
      x_bf, WqkvT, b_qkv, qkv, nullptr, nullptr, nullptr, TOK, D3, DIMSZ);
  norm_rope_kernel<<<TOK, 256, 0, stream>>>(qkv, nq_w, nk_w, rope_cos, rope_sin, Qb, Kb);
  v_transpose_kernel<<<dim3(TOK/64, NHEAD), 256, 0, stream>>>(qkv, Vtb);
  flash_kernel<<<dim3(TOK/64, NHEAD), 256, 0, stream>>>(Qb, Kb, Vtb, gateb, attn_g);
  gemm_bt<1><<<dim3(TOK/128, DIMSZ/128), 256, 0, stream>>>(
      attn_g, WoutT, b_out, nullptr, out, residual, gate_mod, TOK, DIMSZ, DIMSZ);
}

// Round 6
// 295.222 us; speedup vs baseline: 1.0176x; 1.0081x over previous
//
#include <hip/hip_runtime.h>
#include <hip/hip_bf16.h>
#include <cstdint>
#include <cstddef>

#define TOK   2048
#define DIMSZ 2048
#define D3    6144
#define NHEAD 32
#define HDIM  64

typedef __attribute__((ext_vector_type(8))) short bf16x8;
typedef __attribute__((ext_vector_type(8))) unsigned short u16x8;
typedef __attribute__((ext_vector_type(4))) float f32x4;

__device__ __forceinline__ float bf2f(unsigned short u){
  return __uint_as_float(((unsigned)u) << 16);
}
__device__ __forceinline__ unsigned short f2bf(float f){
  unsigned u = __float_as_uint(f);
  u += 0x7fffu + ((u >> 16) & 1u);   // RNE
  return (unsigned short)(u >> 16);
}
__device__ __forceinline__ void gload16(const void* g, void* l){
  __builtin_amdgcn_global_load_lds(
      (const __attribute__((address_space(1))) void*)g,
      (__attribute__((address_space(3))) void*)l, 16, 0, 0);
}
// BUILTIN MFMA everywhere: inline-asm MFMA is opaque to GCNHazardRecognizer
// (manual s_nop padding would be required); builtins get HW hazards handled.
__device__ __forceinline__ void mfma16(bf16x8 a, bf16x8 b, f32x4& c){
  c = __builtin_amdgcn_mfma_f32_16x16x32_bf16(a, b, c, 0, 0, 0);
}

// ---------------- small prep kernels ----------------

__global__ __launch_bounds__(256) void cvt_bf16_kernel(
    const float* __restrict__ in, unsigned short* __restrict__ out, int n8){
  int i = blockIdx.x*256 + threadIdx.x;
  if (i >= n8) return;
  const float4* p = (const float4*)in + (size_t)i*2;
  float4 a = p[0], b = p[1];
  u16x8 o;
  o[0]=f2bf(a.x); o[1]=f2bf(a.y); o[2]=f2bf(a.z); o[3]=f2bf(a.w);
  o[4]=f2bf(b.x); o[5]=f2bf(b.y); o[6]=f2bf(b.z); o[7]=f2bf(b.w);
  *(u16x8*)(out + (size_t)i*8) = o;
}

// fp32 (R x C) -> bf16 (C x R)
__global__ __launch_bounds__(256) void transpose_cvt_kernel(
    const float* __restrict__ in, unsigned short* __restrict__ out, int R, int C){
  __shared__ float tile[32][33];
  int r0 = blockIdx.x*32, c0 = blockIdx.y*32;
  int tc = threadIdx.x & 31, tr = threadIdx.x >> 5;  // tr 0..7
  #pragma unroll
  for (int p=0;p<4;p++){ int r = tr + p*8; tile[r][tc] = in[(size_t)(r0+r)*C + (c0+tc)]; }
  __syncthreads();
  #pragma unroll
  for (int p=0;p<4;p++){ int r = tr + p*8; out[(size_t)(c0+r)*R + (r0+tc)] = f2bf(tile[tc][r]); }
}

__global__ __launch_bounds__(256) void gate_kernel(
    const float* __restrict__ x, const float* __restrict__ Wg,
    const float* __restrict__ bg, float* __restrict__ gate){
  int n = blockIdx.x;
  int h = threadIdx.x >> 3, j = threadIdx.x & 7;
  const float4* xr = (const float4*)(x + (size_t)n*DIMSZ);
  const float4* wr = (const float4*)(Wg + (size_t)h*DIMSZ);
  float s = 0.f;
  #pragma unroll 8
  for (int i=0;i<64;i++){
    float4 a = xr[j + i*8], b = wr[j + i*8];
    s += a.x*b.x + a.y*b.y + a.z*b.z + a.w*b.w;
  }
  s += __shfl_xor(s,1); s += __shfl_xor(s,2); s += __shfl_xor(s,4);
  if (j==0) gate[(size_t)h*TOK + n] = 2.f/(1.f + __expf(-(s + bg[h])));
}

// ---------------- GEMM (m97 structure): C[M,N] = A[M,K] @ Bt[N,K]^T ----------------
template<int MODE>
__global__ __launch_bounds__(256) void gemm_bt(
    const unsigned short* __restrict__ A, const unsigned short* __restrict__ Bt,
    const float* __restrict__ bias,
    unsigned short* __restrict__ Cbf, float* __restrict__ Cf,
    const float* __restrict__ residual, const float* __restrict__ gate_mod,
    int M, int N, int K)
{
  __shared__ __align__(16) unsigned short ldsA[128*32];
  __shared__ __align__(16) unsigned short ldsB[128*32];
  const int tid  = threadIdx.x;
  const int w    = tid >> 6;
  const int lane = tid & 63;
  const int g    = lane >> 4;
  const int li   = lane & 15;
  const int bm   = blockIdx.x * 128;
  const int bn   = blockIdx.y * 128;
  const int wm   = (w >> 1) * 64;
  const int wn   = (w & 1) * 64;

  f32x4 acc[4][4];
  #pragma unroll
  for (int i=0;i<4;i++)
    #pragma unroll
    for (int j=0;j<4;j++)
      acc[i][j] = (f32x4){0.f,0.f,0.f,0.f};

  const int srow = lane >> 2;          // 0..15
  const int scb  = (lane & 3) * 16;    // byte col within 64B tile row

  for (int kt = 0; kt < K; kt += 32){
    #pragma unroll
    for (int i=0;i<2;i++){
      const int chunk = i*4 + w;
      const int row   = chunk*16 + srow;
      gload16((const char*)A  + ((size_t)(bm+row)*K + kt)*2 + scb, (char*)ldsA + chunk*1024);
      gload16((const char*)Bt + ((size_t)(bn+row)*K + kt)*2 + scb, (char*)ldsB + chunk*1024);
    }
    __syncthreads();
    bf16x8 af[4], bfr[4];
    #pragma unroll
    for (int mi=0;mi<4;mi++)
      af[mi] = *(const bf16x8*)((const char*)ldsA + (wm + mi*16 + li)*64 + g*16);
    #pragma unroll
    for (int ni=0;ni<4;ni++)
      bfr[ni] = *(const bf16x8*)((const char*)ldsB + (wn + ni*16 + li)*64 + g*16);
    #pragma unroll
    for (int mi=0;mi<4;mi++)
      #pragma unroll
      for (int ni=0;ni<4;ni++)
        mfma16(af[mi], bfr[ni], acc[mi][ni]);
    __syncthreads();
  }

  #pragma unroll
  for (int ni=0;ni<4;ni++){
    const int col = bn + wn + ni*16 + li;
    const float bv = bias[col];
    const float gm = (MODE==1) ? gate_mod[col] : 0.f;
    #pragma unroll
    for (int mi=0;mi<4;mi++){
      #pragma unroll
      for (int r=0;r<4;r++){
        const int row = bm + wm + mi*16 + g*4 + r;
        const float v = acc[mi][ni][r] + bv;
        if (MODE==0){
          Cbf[(size_t)row*N + col] = f2bf(v);
        } else {
          const size_t idx = (size_t)row*N + col;
          Cf[idx] = residual[idx] + v*gm;
        }
      }
    }
  }
}

// ---------------- RMSNorm + RoPE; Q scaled by (1/8)*log2(e) so softmax runs in exp2 domain ----------------
__global__ __launch_bounds__(256) void norm_rope_kernel(
    const unsigned short* __restrict__ qkv,
    const float* __restrict__ nqw, const float* __restrict__ nkw,
    const float* __restrict__ rc, const float* __restrict__ rsn,
    unsigned short* __restrict__ Q, unsigned short* __restrict__ Ko)
{
  const int n = blockIdx.x, t = threadIdx.x;
  __shared__ float red[4];
  #pragma unroll
  for (int qk=0; qk<2; qk++){
    const unsigned short* row = qkv + (size_t)n*D3 + qk*DIMSZ;
    u16x8 v = *(const u16x8*)(row + t*8);
    float f[8]; float ss = 0.f;
    #pragma unroll
    for (int j=0;j<8;j++){ f[j] = bf2f(v[j]); ss += f[j]*f[j]; }
    #pragma unroll
    for (int msk=1; msk<64; msk<<=1) ss += __shfl_xor(ss, msk);
    if ((t&63)==0) red[t>>6] = ss;
    __syncthreads();
    const float rs = rsqrtf((red[0]+red[1]+red[2]+red[3]) * (1.0f/2048.f) + 1e-6f);
    const int d = t*8, hd = d&63, h = d>>6;
    const int pd = (hd<32) ? d+32 : d-32;
    u16x8 pv = *(const u16x8*)(row + pd);
    const float* wv = qk ? nkw : nqw;
    const float* cs = rc  + n*64 + hd;
    const float* sn = rsn + n*64 + hd;
    const float scl = qk ? 1.f : (0.125f * 1.44269504088896340736f);
    const float sgn = (hd<32) ? -1.f : 1.f;
    u16x8 ov;
    #pragma unroll
    for (int j=0;j<8;j++){
      const float a = f[j]*rs*wv[d+j];
      const float b = bf2f(pv[j])*rs*wv[pd+j];
      ov[j] = f2bf((a*cs[j] + sgn*b*sn[j])*scl);
    }
    unsigned short* dst = (qk ? Ko : Q) + ((size_t)h*TOK + n)*HDIM + hd;
    *(u16x8*)dst = ov;
    __syncthreads();
  }
}

// ---------------- V transpose per head: qkv v-part (N,HD slice) -> Vt (H,HD,N) ----------------
__global__ __launch_bounds__(256) void v_transpose_kernel(
    const unsigned short* __restrict__ qkv, unsigned short* __restrict__ Vt){
  const int h = blockIdx.y, n0 = blockIdx.x*64;
  __shared__ unsigned short tile[64][65];
  const int t = threadIdx.x;
  const int i = t>>2, j0 = (t&3)*16;
  const unsigned short* src = qkv + (size_t)(n0+i)*D3 + 2*DIMSZ + h*HDIM + j0;
  #pragma unroll
  for (int q=0;q<16;q++) tile[i][j0+q] = src[q];
  __syncthreads();
  unsigned short* dst = Vt + ((size_t)h*HDIM + i)*TOK + n0 + j0;
  #pragma unroll
  for (int q=0;q<16;q++) dst[q] = tile[j0+q][i];
}

// ---------------- Flash attention v6: builtin MFMA + dbuf (head + S2 barriers),
// ---------------- exact skip-rescale, packed bf16 converts, exp2 domain, lane-local l ----------------
__global__ __launch_bounds__(256) void flash_kernel(
    const unsigned short* __restrict__ Q, const unsigned short* __restrict__ K,
    const unsigned short* __restrict__ Vt, const float* __restrict__ gate,
    unsigned short* __restrict__ attn_out)
{
  __shared__ __align__(16) unsigned short ldsK[2][64*64];
  __shared__ __align__(16) unsigned short ldsV[2][64*64];
  __shared__ __align__(16) unsigned short ldsP[4*16*64];
  const int tid = threadIdx.x;
  const int w = tid >> 6, lane = tid & 63;
  const int g = lane >> 4, li = lane & 15;
  const int h = blockIdx.y, q0 = blockIdx.x * 64;

  const unsigned short* Qh = Q + (size_t)h*TOK*HDIM;
  bf16x8 qf0, qf1;
  {
    const int qrow = q0 + w*16 + li;
    qf0 = *(const bf16x8*)(Qh + (size_t)qrow*HDIM + g*8);
    qf1 = *(const bf16x8*)(Qh + (size_t)qrow*HDIM + 32 + g*8);
  }
  f32x4 O[4];
  float m_[4], l_[4];
  #pragma unroll
  for (int r=0;r<4;r++){ O[r]=(f32x4){0.f,0.f,0.f,0.f}; m_[r]=-1e30f; l_[r]=0.f; }

  const char* Kh = (const char*)(K  + (size_t)h*TOK*HDIM);   // 128B rows
  const char* Vh = (const char*)(Vt + (size_t)h*HDIM*TOK);   // 4096B rows
  const int srow = lane >> 3;                  // tile row mod 8 during staging
  const int scb  = ((lane & 7) ^ srow) * 16;   // pre-swizzled global source column
  char* pwb = (char*)ldsP + w*2048;
  const int xr = (li & 7) << 4;                // read-side xor for rows == li (mod 8)

  auto stage = [&](int buf, int kt){
    #pragma unroll
    for (int i=0;i<2;i++){
      const int chunk = i*4 + w;
      const int row = chunk*8 + srow;
      gload16(Kh + (size_t)(kt+row)*128 + scb, (char*)ldsK[buf] + chunk*1024);
      gload16(Vh + (size_t)row*4096 + (size_t)kt*2 + scb, (char*)ldsV[buf] + chunk*1024);
    }
  };

  stage(0, 0);
  int cur = 0;
  for (int kt = 0; kt < TOK; kt += 64){
    // HEAD barrier: all waves done with prev tile's PV reads (own ds_reads drained
    // pre-barrier) and prev staging drained (own vmcnt at S2/first-iter here).
    __syncthreads();
    if (kt + 64 < TOK) stage(cur^1, kt + 64);  // flies under QK^T + softmax

    // S = Q(16x64) @ K^T(64x64) in exp2 domain (Q pre-scaled by 0.125*log2e)
    f32x4 sf[4];
    #pragma unroll
    for (int nn=0;nn<4;nn++) sf[nn]=(f32x4){0.f,0.f,0.f,0.f};
    #pragma unroll
    for (int c=0;c<2;c++){
      const bf16x8 qf = c ? qf1 : qf0;
      #pragma unroll
      for (int nn=0;nn<4;nn++){
        const int row = nn*16 + li;
        const bf16x8 kb = *(const bf16x8*)((const char*)ldsK[cur] + row*128 + ((c*64 + g*16) ^ xr));
        mfma16(qf, kb, sf[nn]);
      }
    }

    // full 16-lane max reduce
    float mx[4];
    #pragma unroll
    for (int r=0;r<4;r++)
      mx[r] = fmaxf(fmaxf(sf[0][r], sf[1][r]), fmaxf(sf[2][r], sf[3][r]));
    #pragma unroll
    for (int msk=1; msk<16; msk<<=1){
      #pragma unroll
      for (int r=0;r<4;r++) mx[r] = fmaxf(mx[r], __shfl_xor(mx[r], msk));
    }
    // exact skip-rescale: when no row max increased, al == exp2(0) == 1.0 exactly
    // and x*1.0 is IEEE-exact -> skipping is bit-identical. Branch is wave-uniform.
    const int up = (mx[0] > m_[0]) | (mx[1] > m_[1]) | (mx[2] > m_[2]) | (mx[3] > m_[3]);
    if (__any(up)){
      f32x4 alv;
      #pragma unroll
      for (int r=0;r<4;r++){
        const float nm = fmaxf(m_[r], mx[r]);
        const float al = exp2f(m_[r] - nm);
        m_[r] = nm;
        l_[r] *= al;
        alv[r] = al;
      }
      #pragma unroll
      for (int nn=0;nn<4;nn++) O[nn] *= alv;
    }

    // P = exp2(S - m) <= 1; packed RNE converts (pairs along r); lane-local l
    #pragma unroll
    for (int nn=0;nn<4;nn++){
      float p0 = exp2f(sf[nn][0] - m_[0]);
      float p1 = exp2f(sf[nn][1] - m_[1]);
      float p2 = exp2f(sf[nn][2] - m_[2]);
      float p3 = exp2f(sf[nn][3] - m_[3]);
      l_[0] += p0; l_[1] += p1; l_[2] += p2; l_[3] += p3;
      __hip_bfloat162 h01 = __float22bfloat162_rn(float2{p0, p1});
      __hip_bfloat162 h23 = __float22bfloat162_rn(float2{p2, p3});
      const unsigned u01 = *(const unsigned*)&h01;
      const unsigned u23 = *(const unsigned*)&h23;
      const int pcb = (nn*16 + li)*2;
      *(unsigned short*)(pwb + (g*4+0)*128 + (pcb ^ (((g*4+0)&7)<<4))) = (unsigned short)(u01);
      *(unsigned short*)(pwb + (g*4+1)*128 + (pcb ^ (((g*4+1)&7)<<4))) = (unsigned short)(u01 >> 16);
      *(unsigned short*)(pwb + (g*4+2)*128 + (pcb ^ (((g*4+2)&7)<<4))) = (unsigned short)(u23);
      *(unsigned short*)(pwb + (g*4+3)*128 + (pcb ^ (((g*4+3)&7)<<4))) = (unsigned short)(u23 >> 16);
    }
    // S2 barrier: P visible to all lanes; also drains this iter's staging vmcnt
    __syncthreads();

    // O += P(16x64) @ V(64x64)
    #pragma unroll
    for (int c=0;c<2;c++){
      const bf16x8 pa = *(const bf16x8*)(pwb + li*128 + ((c*64 + g*16) ^ xr));
      #pragma unroll
      for (int nn=0;nn<4;nn++){
        const int row = nn*16 + li;
        const bf16x8 vb = *(const bf16x8*)((const char*)ldsV[cur] + row*128 + ((c*64 + g*16) ^ xr));
        mfma16(pa, vb, O[nn]);
      }
    }
    cur ^= 1;
  }

  // epilogue: single cross-lane sum reduce of l partials
  #pragma unroll
  for (int msk=1; msk<16; msk<<=1){
    #pragma unroll
    for (int r=0;r<4;r++) l_[r] += __shfl_xor(l_[r], msk);
  }
  #pragma unroll
  for (int r=0;r<4;r++){
    const int row = q0 + w*16 + g*4 + r;
    const float gv = gate[(size_t)h*TOK + row];
    const float sc = gv / l_[r];
    #pragma unroll
    for (int nn=0;nn<4;nn++)
      attn_out[(size_t)row*DIMSZ + h*HDIM + nn*16 + li] = f2bf(O[nn][r]*sc);
  }
}

// ---------------- launch ----------------

extern "C" void kernel_launch(void* const* d_in, const int* in_sizes, int n_in,
                              void* d_out, int out_size, void* d_ws, size_t ws_size,
                              hipStream_t stream)
{
  const float* x        = (const float*)d_in[0];
  const float* W_qkv    = (const float*)d_in[1];
  const float* b_qkv    = (const float*)d_in[2];
  const float* nq_w     = (const float*)d_in[3];
  const float* nk_w     = (const float*)d_in[4];
  const float* W_gate   = (const float*)d_in[5];
  const float* b_gate   = (const float*)d_in[6];
  const float* W_out    = (const float*)d_in[7];
  const float* b_out    = (const float*)d_in[8];
  const float* rope_cos = (const float*)d_in[9];
  const float* rope_sin = (const float*)d_in[10];
  const float* residual = (const float*)d_in[11];
  const float* gate_mod = (const float*)d_in[12];
  float* out = (float*)d_out;

  char* p = (char*)d_ws;
  auto take = [&](size_t b)->char*{ char* q = p; p += (b + 255) & ~(size_t)255; return q; };
  unsigned short* x_bf   = (unsigned short*)take((size_t)TOK*DIMSZ*2);
  unsigned short* WqkvT  = (unsigned short*)take((size_t)D3*DIMSZ*2);
  unsigned short* WoutT  = (unsigned short*)take((size_t)DIMSZ*DIMSZ*2);
  unsigned short* qkv    = (unsigned short*)take((size_t)TOK*D3*2);
  unsigned short* Qb     = (unsigned short*)take((size_t)NHEAD*TOK*HDIM*2);
  unsigned short* Kb     = (unsigned short*)take((size_t)NHEAD*TOK*HDIM*2);
  unsigned short* Vtb    = (unsigned short*)take((size_t)NHEAD*HDIM*TOK*2);
  unsigned short* attn_g = (unsigned short*)take((size_t)TOK*DIMSZ*2);
  float*          gateb  = (float*)take((size_t)NHEAD*TOK*4);

  cvt_bf16_kernel<<<(TOK*DIMSZ/8 + 255)/256, 256, 0, stream>>>(x, x_bf, TOK*DIMSZ/8);
  transpose_cvt_kernel<<<dim3(DIMSZ/32, D3/32),   256, 0, stream>>>(W_qkv, WqkvT, DIMSZ, D3);
  transpose_cvt_kernel<<<dim3(DIMSZ/32, DIMSZ/32),256, 0, stream>>>(W_out, WoutT, DIMSZ, DIMSZ);
  gate_kernel<<<TOK, 256, 0, stream>>>(x, W_gate, b_gate, gateb);
  gemm_bt<0><<<dim3(TOK/128, D3/128), 256, 0, stream>>>(
      x_bf, WqkvT, b_qkv, qkv, nullptr, nullptr, nullptr, TOK, D3, DIMSZ);
  norm_rope_kernel<<<TOK, 256, 0, stream>>>(qkv, nq_w, nk_w, rope_cos, rope_sin, Qb, Kb);
  v_transpose_kernel<<<dim3(TOK/64, NHEAD), 256, 0, stream>>>(qkv, Vtb);
  flash_kernel<<<dim3(TOK/64, NHEAD), 256, 0, stream>>>(Qb, Kb, Vtb, gateb, attn_g);
  gemm_bt<1><<<dim3(TOK/128, DIMSZ/128), 256, 0, stream>>>(
      attn_g, WoutT, b_out, nullptr, out, residual, gate_mod, TOK, DIMSZ, DIMSZ);
}

// Round 7
// 271.264 us; speedup vs baseline: 1.1075x; 1.0883x over previous
//
#include <hip/hip_runtime.h>
#include <hip/hip_bf16.h>
#include <cstdint>
#include <cstddef>

#define TOK   2048
#define DIMSZ 2048
#define D3    6144
#define NHEAD 32
#define HDIM  64

typedef __attribute__((ext_vector_type(8)))  short bf16x8;
typedef __attribute__((ext_vector_type(8)))  unsigned short u16x8;
typedef __attribute__((ext_vector_type(4)))  float f32x4;
typedef __attribute__((ext_vector_type(16))) float f32x16;

__device__ __forceinline__ float bf2f(unsigned short u){
  return __uint_as_float(((unsigned)u) << 16);
}
__device__ __forceinline__ unsigned short f2bf(float f){
  unsigned u = __float_as_uint(f);
  u += 0x7fffu + ((u >> 16) & 1u);   // RNE
  return (unsigned short)(u >> 16);
}
__device__ __forceinline__ unsigned pack2bf(float a, float b){
  __hip_bfloat162 h = __float22bfloat162_rn(float2{a, b});
  return *(const unsigned*)&h;
}
__device__ __forceinline__ void gload16(const void* g, void* l){
  __builtin_amdgcn_global_load_lds(
      (const __attribute__((address_space(1))) void*)g,
      (__attribute__((address_space(3))) void*)l, 16, 0, 0);
}
// builtin MFMA only (inline-asm MFMA is opaque to GCNHazardRecognizer — r2-r4 bug)
__device__ __forceinline__ void mfma16(bf16x8 a, bf16x8 b, f32x4& c){
  c = __builtin_amdgcn_mfma_f32_16x16x32_bf16(a, b, c, 0, 0, 0);
}
__device__ __forceinline__ void mfma32(bf16x8 a, bf16x8 b, f32x16& c){
  c = __builtin_amdgcn_mfma_f32_32x32x16_bf16(a, b, c, 0, 0, 0);
}

// ---------------- small prep kernels ----------------

__global__ __launch_bounds__(256) void cvt_bf16_kernel(
    const float* __restrict__ in, unsigned short* __restrict__ out, int n8){
  int i = blockIdx.x*256 + threadIdx.x;
  if (i >= n8) return;
  const float4* p = (const float4*)in + (size_t)i*2;
  float4 a = p[0], b = p[1];
  u16x8 o;
  o[0]=f2bf(a.x); o[1]=f2bf(a.y); o[2]=f2bf(a.z); o[3]=f2bf(a.w);
  o[4]=f2bf(b.x); o[5]=f2bf(b.y); o[6]=f2bf(b.z); o[7]=f2bf(b.w);
  *(u16x8*)(out + (size_t)i*8) = o;
}

// fp32 (R x C) -> bf16 (C x R)
__global__ __launch_bounds__(256) void transpose_cvt_kernel(
    const float* __restrict__ in, unsigned short* __restrict__ out, int R, int C){
  __shared__ float tile[32][33];
  int r0 = blockIdx.x*32, c0 = blockIdx.y*32;
  int tc = threadIdx.x & 31, tr = threadIdx.x >> 5;  // tr 0..7
  #pragma unroll
  for (int p=0;p<4;p++){ int r = tr + p*8; tile[r][tc] = in[(size_t)(r0+r)*C + (c0+tc)]; }
  __syncthreads();
  #pragma unroll
  for (int p=0;p<4;p++){ int r = tr + p*8; out[(size_t)(c0+r)*R + (r0+tc)] = f2bf(tile[tc][r]); }
}

__global__ __launch_bounds__(256) void gate_kernel(
    const float* __restrict__ x, const float* __restrict__ Wg,
    const float* __restrict__ bg, float* __restrict__ gate){
  int n = blockIdx.x;
  int h = threadIdx.x >> 3, j = threadIdx.x & 7;
  const float4* xr = (const float4*)(x + (size_t)n*DIMSZ);
  const float4* wr = (const float4*)(Wg + (size_t)h*DIMSZ);
  float s = 0.f;
  #pragma unroll 8
  for (int i=0;i<64;i++){
    float4 a = xr[j + i*8], b = wr[j + i*8];
    s += a.x*b.x + a.y*b.y + a.z*b.z + a.w*b.w;
  }
  s += __shfl_xor(s,1); s += __shfl_xor(s,2); s += __shfl_xor(s,4);
  if (j==0) gate[(size_t)h*TOK + n] = 2.f/(1.f + __expf(-(s + bg[h])));
}

// ---------------- GEMM (m97 structure): C[M,N] = A[M,K] @ Bt[N,K]^T ----------------
template<int MODE>
__global__ __launch_bounds__(256) void gemm_bt(
    const unsigned short* __restrict__ A, const unsigned short* __restrict__ Bt,
    const float* __restrict__ bias,
    unsigned short* __restrict__ Cbf, float* __restrict__ Cf,
    const float* __restrict__ residual, const float* __restrict__ gate_mod,
    int M, int N, int K)
{
  __shared__ __align__(16) unsigned short ldsA[128*32];
  __shared__ __align__(16) unsigned short ldsB[128*32];
  const int tid  = threadIdx.x;
  const int w    = tid >> 6;
  const int lane = tid & 63;
  const int g    = lane >> 4;
  const int li   = lane & 15;
  const int bm   = blockIdx.x * 128;
  const int bn   = blockIdx.y * 128;
  const int wm   = (w >> 1) * 64;
  const int wn   = (w & 1) * 64;

  f32x4 acc[4][4];
  #pragma unroll
  for (int i=0;i<4;i++)
    #pragma unroll
    for (int j=0;j<4;j++)
      acc[i][j] = (f32x4){0.f,0.f,0.f,0.f};

  const int srow = lane >> 2;          // 0..15
  const int scb  = (lane & 3) * 16;    // byte col within 64B tile row

  for (int kt = 0; kt < K; kt += 32){
    #pragma unroll
    for (int i=0;i<2;i++){
      const int chunk = i*4 + w;
      const int row   = chunk*16 + srow;
      gload16((const char*)A  + ((size_t)(bm+row)*K + kt)*2 + scb, (char*)ldsA + chunk*1024);
      gload16((const char*)Bt + ((size_t)(bn+row)*K + kt)*2 + scb, (char*)ldsB + chunk*1024);
    }
    __syncthreads();
    bf16x8 af[4], bfr[4];
    #pragma unroll
    for (int mi=0;mi<4;mi++)
      af[mi] = *(const bf16x8*)((const char*)ldsA + (wm + mi*16 + li)*64 + g*16);
    #pragma unroll
    for (int ni=0;ni<4;ni++)
      bfr[ni] = *(const bf16x8*)((const char*)ldsB + (wn + ni*16 + li)*64 + g*16);
    #pragma unroll
    for (int mi=0;mi<4;mi++)
      #pragma unroll
      for (int ni=0;ni<4;ni++)
        mfma16(af[mi], bfr[ni], acc[mi][ni]);
    __syncthreads();
  }

  #pragma unroll
  for (int ni=0;ni<4;ni++){
    const int col = bn + wn + ni*16 + li;
    const float bv = bias[col];
    const float gm = (MODE==1) ? gate_mod[col] : 0.f;
    #pragma unroll
    for (int mi=0;mi<4;mi++){
      #pragma unroll
      for (int r=0;r<4;r++){
        const int row = bm + wm + mi*16 + g*4 + r;
        const float v = acc[mi][ni][r] + bv;
        if (MODE==0){
          Cbf[(size_t)row*N + col] = f2bf(v);
        } else {
          const size_t idx = (size_t)row*N + col;
          Cf[idx] = residual[idx] + v*gm;
        }
      }
    }
  }
}

// ---------------- RMSNorm + RoPE; Q scaled by (1/8)*log2(e) so softmax runs in exp2 domain ----------------
__global__ __launch_bounds__(256) void norm_rope_kernel(
    const unsigned short* __restrict__ qkv,
    const float* __restrict__ nqw, const float* __restrict__ nkw,
    const float* __restrict__ rc, const float* __restrict__ rsn,
    unsigned short* __restrict__ Q, unsigned short* __restrict__ Ko)
{
  const int n = blockIdx.x, t = threadIdx.x;
  __shared__ float red[4];
  #pragma unroll
  for (int qk=0; qk<2; qk++){
    const unsigned short* row = qkv + (size_t)n*D3 + qk*DIMSZ;
    u16x8 v = *(const u16x8*)(row + t*8);
    float f[8]; float ss = 0.f;
    #pragma unroll
    for (int j=0;j<8;j++){ f[j] = bf2f(v[j]); ss += f[j]*f[j]; }
    #pragma unroll
    for (int msk=1; msk<64; msk<<=1) ss += __shfl_xor(ss, msk);
    if ((t&63)==0) red[t>>6] = ss;
    __syncthreads();
    const float rs = rsqrtf((red[0]+red[1]+red[2]+red[3]) * (1.0f/2048.f) + 1e-6f);
    const int d = t*8, hd = d&63, h = d>>6;
    const int pd = (hd<32) ? d+32 : d-32;
    u16x8 pv = *(const u16x8*)(row + pd);
    const float* wv = qk ? nkw : nqw;
    const float* cs = rc  + n*64 + hd;
    const float* sn = rsn + n*64 + hd;
    const float scl = qk ? 1.f : (0.125f * 1.44269504088896340736f);
    const float sgn = (hd<32) ? -1.f : 1.f;
    u16x8 ov;
    #pragma unroll
    for (int j=0;j<8;j++){
      const float a = f[j]*rs*wv[d+j];
      const float b = bf2f(pv[j])*rs*wv[pd+j];
      ov[j] = f2bf((a*cs[j] + sgn*b*sn[j])*scl);
    }
    unsigned short* dst = (qk ? Ko : Q) + ((size_t)h*TOK + n)*HDIM + hd;
    *(u16x8*)dst = ov;
    __syncthreads();
  }
}

// ---------------- V transpose per head: qkv v-part (N,HD slice) -> Vt (H,HD,N) ----------------
__global__ __launch_bounds__(256) void v_transpose_kernel(
    const unsigned short* __restrict__ qkv, unsigned short* __restrict__ Vt){
  const int h = blockIdx.y, n0 = blockIdx.x*64;
  __shared__ unsigned short tile[64][65];
  const int t = threadIdx.x;
  const int i = t>>2, j0 = (t&3)*16;
  const unsigned short* src = qkv + (size_t)(n0+i)*D3 + 2*DIMSZ + h*HDIM + j0;
  #pragma unroll
  for (int q=0;q<16;q++) tile[i][j0+q] = src[q];
  __syncthreads();
  unsigned short* dst = Vt + ((size_t)h*HDIM + i)*TOK + n0 + j0;
  #pragma unroll
  for (int q=0;q<16;q++) dst[q] = tile[j0+q][i];
}

// ---------------- Flash attention v7: swapped-operand 32x32 MFMA structure ----------------
// Per wave: 32 q-rows (q = lane&31), KVBLK=64. QK^T swapped -> S^T[kv-reg][q-lane];
// softmax lane-local; P packed in-register, half-exchange via shfl_xor(32);
// PV swapped -> O^T[d-reg][q-lane] (rescale/l/gate all lane-local). One barrier/tile.
__global__ __launch_bounds__(256, 2) void flash_kernel(
    const unsigned short* __restrict__ Q, const unsigned short* __restrict__ K,
    const unsigned short* __restrict__ Vt, const float* __restrict__ gate,
    unsigned short* __restrict__ attn_out)
{
  __shared__ __align__(16) unsigned short ldsK[2][64*64];
  __shared__ __align__(16) unsigned short ldsV[2][64*64];
  const int tid = threadIdx.x;
  const int w = tid >> 6, lane = tid & 63;
  const int q5 = lane & 31, hi = lane >> 5;
  const int h = blockIdx.y, q0 = blockIdx.x * 128;
  const int qrow = q0 + w*32 + q5;

  // Q fragments: B-operand layout = Q[col=lane&31][k=(lane>>5)*8+j]
  const unsigned short* Qh = Q + (size_t)h*TOK*HDIM;
  bf16x8 qf[4];
  #pragma unroll
  for (int ks=0; ks<4; ks++)
    qf[ks] = *(const bf16x8*)(Qh + (size_t)qrow*HDIM + ks*16 + hi*8);

  f32x16 o0 = {}, o1 = {};
  float m_ = -1e30f, l_ = 0.f;

  const char* Kh = (const char*)(K  + (size_t)h*TOK*HDIM);   // 128B rows
  const char* Vh = (const char*)(Vt + (size_t)h*HDIM*TOK);   // 4096B rows
  const int srow = lane >> 3;                  // staging row mod 8
  const int scb  = ((lane & 7) ^ srow) * 16;   // pre-swizzled source column
  const int xr   = (lane & 7) << 4;            // read-side xor (row&7 == lane&7)

  auto stage = [&](int buf, int kt){
    #pragma unroll
    for (int i=0;i<2;i++){
      const int chunk = i*4 + w;
      const int row = chunk*8 + srow;
      gload16(Kh + (size_t)(kt+row)*128 + scb, (char*)ldsK[buf] + chunk*1024);
      gload16(Vh + (size_t)row*4096 + (size_t)kt*2 + scb, (char*)ldsV[buf] + chunk*1024);
    }
  };

  stage(0, 0);
  int cur = 0;
  for (int kt = 0; kt < TOK; kt += 64){
    // single barrier/tile: drains prev prefetch (vmcnt0@barrier) + WAR on buf reuse
    __syncthreads();
    if (kt + 64 < TOK) stage(cur^1, kt + 64);

    // QK^T swapped: s0 = K[kv 0..31] x Q, s1 = K[kv 32..63] x Q  (exp2 domain)
    f32x16 s0 = {}, s1 = {};
    #pragma unroll
    for (int ks=0; ks<4; ks++){
      const int cb = (ks*32 + hi*16) ^ xr;
      const bf16x8 kb0 = *(const bf16x8*)((const char*)ldsK[cur] + q5*128 + cb);
      const bf16x8 kb1 = *(const bf16x8*)((const char*)ldsK[cur] + (32+q5)*128 + cb);
      mfma32(kb0, qf[ks], s0);
      mfma32(kb1, qf[ks], s1);
    }

    // lane-local row max over 32 values + cross-half combine
    float mm = s0[0];
    #pragma unroll
    for (int i=1;i<16;i++) mm = fmaxf(mm, s0[i]);
    #pragma unroll
    for (int i=0;i<16;i++) mm = fmaxf(mm, s1[i]);
    const float rm = fmaxf(mm, __shfl_xor(mm, 32));
    // exact skip-rescale (wave-uniform branch; al==1.0 exactly when skipped)
    if (__any(rm > m_)){
      const float mn = fmaxf(m_, rm);
      const float al = exp2f(m_ - mn);
      m_ = mn; l_ *= al;
      o0 *= al; o1 *= al;
    }

    // P = exp2(S - m): pack pairs to bf16 words; lane-local l accumulation
    unsigned pw[16];
    #pragma unroll
    for (int i=0;i<8;i++){
      const float pa = exp2f(s0[2*i]   - m_);
      const float pb = exp2f(s0[2*i+1] - m_);
      l_ += pa + pb;
      pw[i] = pack2bf(pa, pb);
    }
    #pragma unroll
    for (int i=0;i<8;i++){
      const float pa = exp2f(s1[2*i]   - m_);
      const float pb = exp2f(s1[2*i+1] - m_);
      l_ += pa + pb;
      pw[8+i] = pack2bf(pa, pb);
    }
    // half-exchange: lane l<32 needs partner's words {4k,4k+1}; l>=32 needs {4k+2,4k+3}
    unsigned sw[16];
    #pragma unroll
    for (int i=0;i<16;i++) sw[i] = __shfl_xor(pw[i], 32);

    // PV swapped: O^T += V^T x P^T ; B-frag = P[q=lane&31][kv=16*ks2+hi*8 .. +8]
    #pragma unroll
    for (int ks2=0; ks2<4; ks2++){
      const int b = 4*ks2;
      union { unsigned u[4]; bf16x8 v; } pf;
      pf.u[0] = hi ? sw[b+2] : pw[b];
      pf.u[1] = hi ? sw[b+3] : pw[b+1];
      pf.u[2] = hi ? pw[b+2] : sw[b];
      pf.u[3] = hi ? pw[b+3] : sw[b+1];
      const int cb = (ks2*32 + hi*16) ^ xr;
      const bf16x8 vb0 = *(const bf16x8*)((const char*)ldsV[cur] + q5*128 + cb);
      const bf16x8 vb1 = *(const bf16x8*)((const char*)ldsV[cur] + (32+q5)*128 + cb);
      mfma32(vb0, pf.v, o0);
      mfma32(vb1, pf.v, o1);
    }
    cur ^= 1;
  }

  // epilogue: combine l across halves; scale by gate/l; write O^T[d-reg][q-lane]
  const float lt = l_ + __shfl_xor(l_, 32);
  const float sc = gate[(size_t)h*TOK + qrow] / lt;
  o0 *= sc; o1 *= sc;
  unsigned short* orow = attn_out + (size_t)qrow*DIMSZ + h*HDIM;
  #pragma unroll
  for (int j=0;j<4;j++){
    const int d0 = 8*j + 4*hi;
    uint2 v0, v1;
    v0.x = pack2bf(o0[4*j],   o0[4*j+1]);
    v0.y = pack2bf(o0[4*j+2], o0[4*j+3]);
    v1.x = pack2bf(o1[4*j],   o1[4*j+1]);
    v1.y = pack2bf(o1[4*j+2], o1[4*j+3]);
    *(uint2*)(orow + d0)      = v0;
    *(uint2*)(orow + 32 + d0) = v1;
  }
}

// ---------------- launch ----------------

extern "C" void kernel_launch(void* const* d_in, const int* in_sizes, int n_in,
                              void* d_out, int out_size, void* d_ws, size_t ws_size,
                              hipStream_t stream)
{
  const float* x        = (const float*)d_in[0];
  const float* W_qkv    = (const float*)d_in[1];
  const float* b_qkv    = (const float*)d_in[2];
  const float* nq_w     = (const float*)d_in[3];
  const float* nk_w     = (const float*)d_in[4];
  const float* W_gate   = (const float*)d_in[5];
  const float* b_gate   = (const float*)d_in[6];
  const float* W_out    = (const float*)d_in[7];
  const float* b_out    = (const float*)d_in[8];
  const float* rope_cos = (const float*)d_in[9];
  const float* rope_sin = (const float*)d_in[10];
  const float* residual = (const float*)d_in[11];
  const float* gate_mod = (const float*)d_in[12];
  float* out = (float*)d_out;

  char* p = (char*)d_ws;
  auto take = [&](size_t b)->char*{ char* q = p; p += (b + 255) & ~(size_t)255; return q; };
  unsigned short* x_bf   = (unsigned short*)take((size_t)TOK*DIMSZ*2);
  unsigned short* WqkvT  = (unsigned short*)take((size_t)D3*DIMSZ*2);
  unsigned short* WoutT  = (unsigned short*)take((size_t)DIMSZ*DIMSZ*2);
  unsigned short* qkv    = (unsigned short*)take((size_t)TOK*D3*2);
  unsigned short* Qb     = (unsigned short*)take((size_t)NHEAD*TOK*HDIM*2);
  unsigned short* Kb     = (unsigned short*)take((size_t)NHEAD*TOK*HDIM*2);
  unsigned short* Vtb    = (unsigned short*)take((size_t)NHEAD*HDIM*TOK*2);
  unsigned short* attn_g = (unsigned short*)take((size_t)TOK*DIMSZ*2);
  float*          gateb  = (float*)take((size_t)NHEAD*TOK*4);

  cvt_bf16_kernel<<<(TOK*DIMSZ/8 + 255)/256, 256, 0, stream>>>(x, x_bf, TOK*DIMSZ/8);
  transpose_cvt_kernel<<<dim3(DIMSZ/32, D3/32),   256, 0, stream>>>(W_qkv, WqkvT, DIMSZ, D3);
  transpose_cvt_kernel<<<dim3(DIMSZ/32, DIMSZ/32),256, 0, stream>>>(W_out, WoutT, DIMSZ, DIMSZ);
  gate_kernel<<<TOK, 256, 0, stream>>>(x, W_gate, b_gate, gateb);
  gemm_bt<0><<<dim3(TOK/128, D3/128), 256, 0, stream>>>(
      x_bf, WqkvT, b_qkv, qkv, nullptr, nullptr, nullptr, TOK, D3, DIMSZ);
  norm_rope_kernel<<<TOK, 256, 0, stream>>>(qkv, nq_w, nk_w, rope_cos, rope_sin, Qb, Kb);
  v_transpose_kernel<<<dim3(TOK/64, NHEAD), 256, 0, stream>>>(qkv, Vtb);
  flash_kernel<<<dim3(TOK/128, NHEAD), 256, 0, stream>>>(Qb, Kb, Vtb, gateb, attn_g);
  gemm_bt<1><<<dim3(TOK/128, DIMSZ/128), 256, 0, stream>>>(
      attn_g, WoutT, b_out, nullptr, out, residual, gate_mod, TOK, DIMSZ, DIMSZ);
}